// Round 14
// baseline (238.469 us; speedup 1.0000x reference)
//
#include <hip/hip_runtime.h>

// Deformable conv v1 fwd: B=4, C=64, H=W=128, K=3, O=64, fp32 in/out.
// bf16 split MFMA (A=weights hi+lo, B=data single RNE bf16).
// 3-kernel graph:
//   K1 prep_and_transpose (R13-verified): weight planes + NCHW->NHWC.
//   K2 offset_conv (R10-verified verbatim): offset GEMM, 512 blocks.
//   K3 dcn_main v2: Phase B coef tables -> BARRIER-FREE tap loop.
//      Lane = (pixel lm, channel-chunk 8*lg) builds B-frags in registers;
//      wave owns 16 px x all 64 o. No LDS staging, no barriers in loop.
//
// ws layout (bytes):
//   [0)        whi   u16[9][64][64]   (w: [tap][o][c] hi plane)
//   [73728)    wlo   u16[9][64][64]
//   [147456)   wofh  u16[9][32][64]   (w_off padded 18->32, [tap][ch][c])
//   [184320)   wofl  u16[9][32][64]
//   [221184)   xt    f32[4][128][128][64]  (NHWC)
//   [16998400) off_pix f32[4][128][128][18]
//   end 21716992 (~20.7 MB)

typedef unsigned short u16;
typedef __attribute__((ext_vector_type(8))) short bf16x8;
typedef __attribute__((ext_vector_type(4))) float f32x4;
#define MFMA __builtin_amdgcn_mfma_f32_16x16x32_bf16

__device__ __forceinline__ void bsplit(float v, u16& h, u16& l) {
  unsigned u = __float_as_uint(v);
  unsigned hb = (u + 0x7fffu + ((u >> 16) & 1u)) & 0xffff0000u;
  h = (u16)(hb >> 16);
  float r = v - __uint_as_float(hb);
  unsigned u2 = __float_as_uint(r);
  l = (u16)((u2 + 0x7fffu + ((u2 >> 16) & 1u)) >> 16);
}

__device__ __forceinline__ u16 brnd(float v) {   // fp32 -> bf16 RNE
  unsigned u = __float_as_uint(v);
  return (u16)((u + 0x7fffu + ((u >> 16) & 1u)) >> 16);
}

// K1: blocks [0,1024): NCHW->NHWC transpose; blocks [1024,1088): weight prep.
__global__ __launch_bounds__(256) void prep_and_transpose(
    const float* __restrict__ x, const float* __restrict__ w,
    const float* __restrict__ w_off, float* __restrict__ xt,
    u16* __restrict__ whi, u16* __restrict__ wlo,
    u16* __restrict__ wofh, u16* __restrict__ wofl) {
  __shared__ float tile[64][65];
  int blk = blockIdx.x;
  if (blk < 1024) {
    int wchunk = blk & 1;
    int h = (blk >> 1) & 127;
    int b = blk >> 8;
    int w0 = wchunk * 64;
    int r = threadIdx.x >> 6;
    int lane = threadIdx.x & 63;
#pragma unroll
    for (int i = 0; i < 16; i++) {
      int c = r + i * 4;
      tile[c][lane] = x[(((size_t)(b * 64 + c) * 128) + h) * 128 + w0 + lane];
    }
    __syncthreads();
#pragma unroll
    for (int i = 0; i < 16; i++) {
      int wi = r + i * 4;
      xt[(((size_t)(b * 128 + h) * 128) + w0 + wi) * 64 + lane] = tile[lane][wi];
    }
  } else {
    int t = (blk - 1024) * 256 + threadIdx.x;
    const int stride = 64 * 256;
    for (int i = t; i < 9 * 64 * 64; i += stride) {
      int tap = i >> 12, o = (i >> 6) & 63, c = i & 63;
      u16 h, l;
      bsplit(w[o * 576 + c * 9 + tap], h, l);
      whi[i] = h; wlo[i] = l;
    }
    for (int i = t; i < 9 * 32 * 64; i += stride) {
      int tap = i >> 11, ch = (i >> 6) & 31, c = i & 63;
      float v = (ch < 18) ? w_off[ch * 576 + c * 9 + tap] : 0.f;
      u16 h, l;
      bsplit(v, h, l);
      wofh[i] = h; wofl[i] = l;
    }
  }
}

// K2: offset conv as MFMA GEMM (R10 verbatim, known good). 512 blocks.
__global__ __launch_bounds__(256) void offset_conv(
    const float* __restrict__ xt, const u16* __restrict__ wofh,
    const u16* __restrict__ wofl, const float* __restrict__ b_off,
    float* __restrict__ off_pix) {
  int blk = blockIdx.x;            // 512 = b*128 + h
  int h = blk & 127, b = blk >> 7;
  int lane = threadIdx.x & 63, wv = threadIdx.x >> 6;
  int lm = lane & 15, lg = lane >> 4;
  const float* xb = xt + (size_t)b * (128 * 128 * 64);

  f32x4 acc[2][2];
#pragma unroll
  for (int i = 0; i < 2; i++)
#pragma unroll
    for (int j = 0; j < 2; j++) acc[i][j] = (f32x4)0.f;

#pragma unroll 1
  for (int tap = 0; tap < 9; tap++) {
    int ky = tap / 3, kx = tap - ky * 3;
    int y = h + ky - 1;
    if ((unsigned)y >= 128u) continue;           // block-uniform
#pragma unroll
    for (int kc = 0; kc < 2; kc++) {
      const u16* ah = wofh + tap * 2048 + lm * 64 + kc * 32 + lg * 8;
      const u16* al = wofl + tap * 2048 + lm * 64 + kc * 32 + lg * 8;
      bf16x8 a0h = *(const bf16x8*)ah;
      bf16x8 a0l = *(const bf16x8*)al;
      bf16x8 a1h = *(const bf16x8*)(ah + 1024);
      bf16x8 a1l = *(const bf16x8*)(al + 1024);
#pragma unroll
      for (int pt = 0; pt < 2; pt++) {
        int xx = wv * 32 + pt * 16 + lm + kx - 1;
        bool valid = (unsigned)xx < 128u;
        int xc = min(max(xx, 0), 127);
        const float* xp = xb + ((size_t)(y * 128 + xc)) * 64 + kc * 32 + lg * 8;
        float4 xa = *(const float4*)xp;
        float4 xd = *(const float4*)(xp + 4);
        if (!valid) { xa = make_float4(0, 0, 0, 0); xd = make_float4(0, 0, 0, 0); }
        bf16x8 bh;
        bh[0] = brnd(xa.x); bh[1] = brnd(xa.y);
        bh[2] = brnd(xa.z); bh[3] = brnd(xa.w);
        bh[4] = brnd(xd.x); bh[5] = brnd(xd.y);
        bh[6] = brnd(xd.z); bh[7] = brnd(xd.w);
        acc[pt][0] = MFMA(a0h, bh, acc[pt][0], 0, 0, 0);
        acc[pt][0] = MFMA(a0l, bh, acc[pt][0], 0, 0, 0);
        acc[pt][1] = MFMA(a1h, bh, acc[pt][1], 0, 0, 0);
        acc[pt][1] = MFMA(a1l, bh, acc[pt][1], 0, 0, 0);
      }
    }
  }

  float4 bo = *(const float4*)(b_off + 4 * lg);
  float b16 = b_off[16], b17 = b_off[17];
#pragma unroll
  for (int pt = 0; pt < 2; pt++) {
    int wc = wv * 32 + pt * 16 + lm;
    size_t base = ((size_t)((b * 128 + h) * 128) + wc) * 18;
    float2 s0 = make_float2(acc[pt][0][0] + bo.x, acc[pt][0][1] + bo.y);
    float2 s1 = make_float2(acc[pt][0][2] + bo.z, acc[pt][0][3] + bo.w);
    *(float2*)(off_pix + base + 4 * lg) = s0;
    *(float2*)(off_pix + base + 4 * lg + 2) = s1;
    if (lg == 0) {
      float2 s2 = make_float2(acc[pt][1][0] + b16, acc[pt][1][1] + b17);
      *(float2*)(off_pix + base + 16) = s2;
    }
  }
}

// K3: bilinear sample + split MFMA GEMM, BARRIER-FREE tap loop.
// Lane (lm,lg): pixel px = wave*16+lm, channels {8lg..8lg+7} and {32+8lg..}.
// Wave computes all 64 o for its 16 px. acc[ot][r] = out[o=ot*16+4lg+r][px].
__global__ __launch_bounds__(256) void dcn_main(
    const float* __restrict__ xt, const float* __restrict__ off_pix,
    const u16* __restrict__ whi, const u16* __restrict__ wlo,
    const float* __restrict__ bias, float* __restrict__ out) {
  __shared__ __align__(16) float cw_lds[576][4];   // bilinear weights
  __shared__ __align__(16) int   ci_lds[576][4];   // corner float-index offsets

  int blk = blockIdx.x;
  int wg = ((blk & 7) << 7) | (blk >> 3);          // bijective XCD chunk swizzle
  int wc = wg & 1, h = (wg >> 1) & 127, b = wg >> 8;
  int w0 = wc * 64;
  int tid = threadIdx.x, lane = tid & 63, wave = tid >> 6;
  int lm = lane & 15, lg = lane >> 4;
  const float* xbase = xt + (size_t)b * (128 * 128 * 64);
  const float* offbase = off_pix + (size_t)((b * 128 + h) * 128 + w0) * 18;

  // ---- Phase B: coef tables (R10 math, element offsets) ----
#pragma unroll 1
  for (int it = tid; it < 576; it += 256) {
    int p = it / 9, k = it - p * 9;
    int ky = k / 3, kx = k - ky * 3;
    float2 o2 = *reinterpret_cast<const float2*>(offbase + p * 18 + 2 * k);
    float yf = (float)(h + ky - 1) + o2.x;
    float xf = (float)(w0 + p + kx - 1) + o2.y;
    float y0f = floorf(yf), x0f = floorf(xf);
    float wy = yf - y0f, wx = xf - x0f;
    int y0 = (int)y0f, x0 = (int)x0f;
    int y1 = y0 + 1, x1 = x0 + 1;
    float w00 = (1.f - wy) * (1.f - wx);
    float w01 = (1.f - wy) * wx;
    float w10 = wy * (1.f - wx);
    float w11 = wy * wx;
    bool vy0 = (unsigned)y0 < 128u, vy1 = (unsigned)y1 < 128u;
    bool vx0 = (unsigned)x0 < 128u, vx1 = (unsigned)x1 < 128u;
    if (!(vy0 && vx0)) w00 = 0.f;
    if (!(vy0 && vx1)) w01 = 0.f;
    if (!(vy1 && vx0)) w10 = 0.f;
    if (!(vy1 && vx1)) w11 = 0.f;
    int y0c = min(max(y0, 0), 127), y1c = min(max(y1, 0), 127);
    int x0c = min(max(x0, 0), 127), x1c = min(max(x1, 0), 127);
    *(float4*)cw_lds[it] = make_float4(w00, w01, w10, w11);
    *(int4*)ci_lds[it] =
        make_int4((y0c * 128 + x0c) * 64, (y0c * 128 + x1c) * 64,
                  (y1c * 128 + x0c) * 64, (y1c * 128 + x1c) * 64);
  }
  __syncthreads();   // coef tables read-only from here on

  int px9 = (wave * 16 + lm) * 9;
  int cA = lg * 8;          // kc0 channel base
  int cB = 32 + lg * 8;     // kc1 channel base

  f32x4 acc[4];
#pragma unroll
  for (int i = 0; i < 4; i++) acc[i] = (f32x4)0.f;

  float4 cor[16];           // 4 corners x {kc0 lo, kc0 hi, kc1 lo, kc1 hi}
  bf16x8 b0, b1;            // current tap's B-fragments

#define GATHER(T)                                                         \
  {                                                                       \
    int4 ci = *(const int4*)ci_lds[px9 + (T)];                            \
    const float* p0 = xbase + ci.x;                                       \
    const float* p1 = xbase + ci.y;                                       \
    const float* p2 = xbase + ci.z;                                       \
    const float* p3 = xbase + ci.w;                                       \
    cor[0]  = *(const float4*)(p0 + cA); cor[1]  = *(const float4*)(p0 + cA + 4); \
    cor[2]  = *(const float4*)(p0 + cB); cor[3]  = *(const float4*)(p0 + cB + 4); \
    cor[4]  = *(const float4*)(p1 + cA); cor[5]  = *(const float4*)(p1 + cA + 4); \
    cor[6]  = *(const float4*)(p1 + cB); cor[7]  = *(const float4*)(p1 + cB + 4); \
    cor[8]  = *(const float4*)(p2 + cA); cor[9]  = *(const float4*)(p2 + cA + 4); \
    cor[10] = *(const float4*)(p2 + cB); cor[11] = *(const float4*)(p2 + cB + 4); \
    cor[12] = *(const float4*)(p3 + cA); cor[13] = *(const float4*)(p3 + cA + 4); \
    cor[14] = *(const float4*)(p3 + cB); cor[15] = *(const float4*)(p3 + cB + 4); \
  }

#define COMBINE(T)                                                        \
  {                                                                       \
    float4 cwv = *(const float4*)cw_lds[px9 + (T)];                       \
    float v[16];                                                          \
    _Pragma("unroll")                                                     \
    for (int q = 0; q < 4; q++) {                                         \
      const float* c0 = (const float*)&cor[q];                            \
      const float* c1 = (const float*)&cor[4 + q];                        \
      const float* c2 = (const float*)&cor[8 + q];                        \
      const float* c3 = (const float*)&cor[12 + q];                       \
      _Pragma("unroll")                                                   \
      for (int j = 0; j < 4; j++)                                         \
        v[q * 4 + j] = cwv.x * c0[j] + cwv.y * c1[j] +                    \
                       cwv.z * c2[j] + cwv.w * c3[j];                     \
    }                                                                     \
    _Pragma("unroll")                                                     \
    for (int j = 0; j < 8; j++) { b0[j] = brnd(v[j]); b1[j] = brnd(v[8 + j]); } \
  }

#define MFMAPHASE(T)                                                      \
  {                                                                       \
    _Pragma("unroll")                                                     \
    for (int ot = 0; ot < 4; ot++) {                                      \
      const u16* wh = whi + (T) * 4096 + (ot * 16 + lm) * 64 + lg * 8;    \
      const u16* wl = wlo + (T) * 4096 + (ot * 16 + lm) * 64 + lg * 8;    \
      bf16x8 ah0 = *(const bf16x8*)wh;                                    \
      bf16x8 ah1 = *(const bf16x8*)(wh + 32);                             \
      bf16x8 al0 = *(const bf16x8*)wl;                                    \
      bf16x8 al1 = *(const bf16x8*)(wl + 32);                             \
      acc[ot] = MFMA(ah0, b0, acc[ot], 0, 0, 0);                          \
      acc[ot] = MFMA(al0, b0, acc[ot], 0, 0, 0);                          \
      acc[ot] = MFMA(ah1, b1, acc[ot], 0, 0, 0);                          \
      acc[ot] = MFMA(al1, b1, acc[ot], 0, 0, 0);                          \
    }                                                                     \
  }

  GATHER(0);
  COMBINE(0);
#pragma unroll 1
  for (int t = 0; t < 8; ++t) {
    GATHER(t + 1);     // issue next tap's 16 loads (independent of MFMA)
    MFMAPHASE(t);      // consume b0,b1 for tap t
    COMBINE(t + 1);    // waits on loads, builds next b0,b1
  }
  MFMAPHASE(8);

  // ---- store: acc[ot][r] = out[o = ot*16 + 4lg + r][px = wave*16 + lm] ----
#pragma unroll
  for (int ot = 0; ot < 4; ot++) {
    float4 bv = *(const float4*)(bias + ot * 16 + 4 * lg);
    size_t ob = ((size_t)(b * 64 + ot * 16 + 4 * lg)) * 16384 + h * 128 + w0 +
                wave * 16 + lm;
#pragma unroll
    for (int r = 0; r < 4; r++) {
      float bb = (r == 0) ? bv.x : (r == 1) ? bv.y : (r == 2) ? bv.z : bv.w;
      out[ob + (size_t)r * 16384] = acc[ot][r] + bb;
    }
  }
#undef GATHER
#undef COMBINE
#undef MFMAPHASE
}

extern "C" void kernel_launch(void* const* d_in, const int* in_sizes, int n_in,
                              void* d_out, int out_size, void* d_ws, size_t ws_size,
                              hipStream_t stream) {
  const float* x     = (const float*)d_in[0];
  const float* w_off = (const float*)d_in[1];
  const float* b_off = (const float*)d_in[2];
  const float* w     = (const float*)d_in[3];
  const float* b     = (const float*)d_in[4];
  float* out = (float*)d_out;
  char* ws = (char*)d_ws;

  u16*   whi     = (u16*)(ws);
  u16*   wlo     = (u16*)(ws + 73728);
  u16*   wofh    = (u16*)(ws + 147456);
  u16*   wofl    = (u16*)(ws + 184320);
  float* xtw     = (float*)(ws + 221184);
  float* off_pix = (float*)(ws + 16998400);

  prep_and_transpose<<<1088, 256, 0, stream>>>(x, w, w_off, xtw, whi, wlo, wofh, wofl);
  offset_conv<<<512, 256, 0, stream>>>(xtw, wofh, wofl, b_off, off_pix);
  dcn_main<<<1024, 256, 0, stream>>>(xtw, off_pix, whi, wlo, b, out);
}